// Round 9
// baseline (293.758 us; speedup 1.0000x reference)
//
#include <hip/hip_runtime.h>
#include <cstdint>
#include <cstddef>

typedef __bf16 bf16x8 __attribute__((ext_vector_type(8)));
typedef float f32x4 __attribute__((ext_vector_type(4)));
typedef unsigned short u16;
typedef unsigned short u16x8 __attribute__((ext_vector_type(8)));

#define BATCH 4096
#define NE 8

__device__ __forceinline__ u16 f2bf(float f) {
  union { float f; uint32_t u; } v; v.f = f;
  uint32_t u = v.u;
  u += 0x7fffu + ((u >> 16) & 1u);   // RTNE
  return (u16)(u >> 16);
}

__device__ __forceinline__ float bf2f(u16 u) {
  union { uint32_t u; float f; } v; v.u = ((uint32_t)u) << 16;
  return v.f;
}

__device__ __forceinline__ void cast8(const float* src, u16* dst) {
  const float4* p = (const float4*)src;
  float4 a = p[0], b = p[1];
  u16x8 o;
  o[0] = f2bf(a.x); o[1] = f2bf(a.y); o[2] = f2bf(a.z); o[3] = f2bf(a.w);
  o[4] = f2bf(b.x); o[5] = f2bf(b.y); o[6] = f2bf(b.z); o[7] = f2bf(b.w);
  *(u16x8*)dst = o;
}

// Fragment-major layout: 1KB chunk c = 64 lanes x 16B. For a 16-row tile rt and
// 32-wide K block kb: lane l holds row rt*16+(l&15), k = kb*32+((l>>4)<<3)..+8.
// A-side chunk index: c = rowt*KB + kb. B-side: c = (e*(N/16)+colt)*KB + kb.
// A wave's MFMA fragment load is then ONE coalesced global_load_dwordx4.

__global__ void prep_kernel(const float* __restrict__ x,
                            const float* __restrict__ W0,
                            const float* __restrict__ W1,
                            const float* __restrict__ W2,
                            u16* __restrict__ h0f, u16* __restrict__ Bt0,
                            u16* __restrict__ Bt1, u16* __restrict__ Bt2) {
  int t = blockIdx.x * blockDim.x + threadIdx.x;
  const int C0 = 262144;             // x:  4096x512 /8
  const int C1 = C0 + 524288;        // W0: 8x1024x512 /8
  const int C2 = C1 + 1048576;       // W1: 8x1024x1024 /8
  if (t < C0) {                      // x -> A-frag-major, K=512, KB=16
    int lane = t & 63, c = t >> 6;
    int rowt = c >> 4, kb = c & 15;
    const float* s = x + ((size_t)(rowt * 16 + (lane & 15)) * 512 + kb * 32 + ((lane >> 4) << 3));
    cast8(s, h0f + (size_t)c * 512 + (lane << 3));
  } else if (t < C1) {               // W0: N=1024, K0=512, KB=16, NT=64
    int u = t - C0, lane = u & 63, c = u >> 6;
    int kb = c & 15, c2 = c >> 4;
    int colt = c2 & 63, e = c2 >> 6;
    const float* s = W0 + (((size_t)e * 1024 + colt * 16 + (lane & 15)) * 512 + kb * 32 + ((lane >> 4) << 3));
    cast8(s, Bt0 + (size_t)c * 512 + (lane << 3));
  } else if (t < C2) {               // W1: N=1024, K0=1024, KB=32, NT=64
    int u = t - C1, lane = u & 63, c = u >> 6;
    int kb = c & 31, c2 = c >> 5;
    int colt = c2 & 63, e = c2 >> 6;
    const float* s = W1 + (((size_t)e * 1024 + colt * 16 + (lane & 15)) * 1024 + kb * 32 + ((lane >> 4) << 3));
    cast8(s, Bt1 + (size_t)c * 512 + (lane << 3));
  } else {                           // W2: N=512, K0=1024, KB=32, NT=32
    int u = t - C2, lane = u & 63, c = u >> 6;
    int kb = c & 31, c2 = c >> 5;
    int colt = c2 & 31, e = c2 >> 5;
    const float* s = W2 + (((size_t)e * 512 + colt * 16 + (lane & 15)) * 1024 + kb * 32 + ((lane >> 4) << 3));
    cast8(s, Bt2 + (size_t)c * 512 + (lane << 3));
  }
}

// out = [act](sum_s P_s + blend @ Bias). KN>0: write bf16 A-frag-major for a
// next layer with K=KN. KN==0: write fp32 row-major (final output).
template<int SLICES, bool ELU_ACT, int KN>
__global__ void combineS_kernel(const u16* __restrict__ P,
                                const float* __restrict__ blend,
                                const float* __restrict__ Bias,
                                void* __restrict__ outp, int N) {
  int t = blockIdx.x * blockDim.x + threadIdx.x;
  int per_row = N >> 3;
  int b = t / per_row;
  int i0 = (t - b * per_row) << 3;
  const size_t slice = (size_t)BATCH * N;
  float v[8] = {0, 0, 0, 0, 0, 0, 0, 0};
  #pragma unroll
  for (int s = 0; s < SLICES; ++s) {
    u16x8 pv = *(const u16x8*)(P + (size_t)s * slice + (size_t)b * N + i0);
    #pragma unroll
    for (int j = 0; j < 8; ++j) v[j] += bf2f(pv[j]);
  }
  const float4* blp = (const float4*)(blend + b * NE);
  float4 u0 = blp[0], u1 = blp[1];
  float bl[8] = {u0.x, u0.y, u0.z, u0.w, u1.x, u1.y, u1.z, u1.w};
  #pragma unroll
  for (int e = 0; e < NE; ++e) {
    const float4* bp = (const float4*)(Bias + (size_t)e * N + i0);
    float4 ba = bp[0], bb = bp[1];
    float bv[8] = {ba.x, ba.y, ba.z, ba.w, bb.x, bb.y, bb.z, bb.w};
    #pragma unroll
    for (int j = 0; j < 8; ++j) v[j] += bl[e] * bv[j];
  }
  if (ELU_ACT) {
    #pragma unroll
    for (int j = 0; j < 8; ++j) v[j] = v[j] > 0.f ? v[j] : expm1f(v[j]);
  }
  if (KN > 0) {
    u16x8 o;
    #pragma unroll
    for (int j = 0; j < 8; ++j) o[j] = f2bf(v[j]);
    int rowt = b >> 4, kb = i0 >> 5;
    int lane = (b & 15) + (((i0 >> 3) & 3) << 4);
    *(u16x8*)((u16*)outp + ((size_t)(rowt * (KN >> 5) + kb)) * 512 + (lane << 3)) = o;
  } else {
    float4* op = (float4*)((float*)outp + (size_t)b * N + i0);
    op[0] = (float4){v[0], v[1], v[2], v[3]};
    op[1] = (float4){v[4], v[5], v[6], v[7]};
  }
}

// Barrier-free flatmm GEMM (AITER pattern): P_z = sum_{e in z} t_e*(h @ W_e^T).
// Both operands in frag-major layout -> each fragment is one coalesced
// global_load_dwordx4; NO LDS staging, NO __syncthreads in the K-loop, so no
// forced vmcnt(0) drain — the compiler pipelines loads against MFMAs.
// Expert blending via telescoping rescale: after expert e's K-loop,
// acc *= t_e/t_{e+1} (last: *t_last), t=max(blend,1e-30). acc only: 64 AGPR.
template<int K0, int EPB>
__global__ __launch_bounds__(256, 2)
void gemm_ff_kernel(const u16* __restrict__ Af, const u16* __restrict__ Btf,
                    const float* __restrict__ blend, u16* __restrict__ P, int N) {
  constexpr int KB = K0 / 32;
  __shared__ float rat[128 * EPB];
  __shared__ __align__(16) u16 ls[4 * 2048];

  const int tid  = threadIdx.x;
  const int w    = tid >> 6, lane = tid & 63;
  const int wm   = w >> 1,   wn   = w & 1;
  const int lrow = lane & 15, quad = lane >> 4;
  const int row0 = blockIdx.x * 128;
  const int col0 = blockIdx.y * 128;
  const int e0   = blockIdx.z * EPB;
  const int NT   = N >> 4;

  // telescoping ratio table: rat[row][j] = t_{e0+j}/t_{e0+j+1}; last = t_last
  for (int t = tid; t < 128 * EPB; t += 256) {
    int row = t / EPB, j = t % EPB;
    float sa = fmaxf(blend[(size_t)(row0 + row) * NE + e0 + j], 1e-30f);
    float sb = (j < EPB - 1) ? fmaxf(blend[(size_t)(row0 + row) * NE + e0 + j + 1], 1e-30f) : 1.0f;
    rat[t] = sa / sb;
  }
  __syncthreads();   // the only block-wide barrier

  const u16* aA[4];
  const u16* aB[4];
  #pragma unroll
  for (int i = 0; i < 4; ++i) {
    aA[i] = Af  + ((size_t)(blockIdx.x * 8 + wm * 4 + i) * KB) * 512 + (lane << 3);
    aB[i] = Btf + ((size_t)((e0 * NT) + blockIdx.y * 8 + wn * 4 + i) * KB) * 512 + (lane << 3);
  }

  f32x4 acc[4][4];
  #pragma unroll
  for (int i = 0; i < 4; ++i)
    #pragma unroll
    for (int j = 0; j < 4; ++j) acc[i][j] = (f32x4){0.f, 0.f, 0.f, 0.f};

  #pragma unroll 1
  for (int ee = 0; ee < EPB; ++ee) {
    #pragma unroll 1
    for (int kq = 0; kq < KB / 4; ++kq) {
      #pragma unroll
      for (int u = 0; u < 4; ++u) {     // imm offsets 0,1024,2048,3072 B
        bf16x8 fa[4], fb[4];
        #pragma unroll
        for (int i = 0; i < 4; ++i) fa[i] = *(const bf16x8*)(aA[i] + u * 512);
        #pragma unroll
        for (int j = 0; j < 4; ++j) fb[j] = *(const bf16x8*)(aB[j] + u * 512);
        #pragma unroll
        for (int i = 0; i < 4; ++i)
          #pragma unroll
          for (int j = 0; j < 4; ++j)
            acc[i][j] = __builtin_amdgcn_mfma_f32_16x16x32_bf16(fa[i], fb[j], acc[i][j], 0, 0, 0);
      }
      #pragma unroll
      for (int i = 0; i < 4; ++i) { aA[i] += 2048; aB[i] += 2048; }
    }
    // rescale acc into next expert's scaled space
    #pragma unroll
    for (int mt = 0; mt < 4; ++mt) {
      float rr[4];
      #pragma unroll
      for (int r = 0; r < 4; ++r)
        rr[r] = rat[(wm * 64 + mt * 16 + quad * 4 + r) * EPB + ee];
      #pragma unroll
      for (int nt = 0; nt < 4; ++nt)
        #pragma unroll
        for (int r = 0; r < 4; ++r)
          acc[mt][nt][r] *= rr[r];
    }
    // A back to k=0; B on to next expert
    #pragma unroll
    for (int i = 0; i < 4; ++i) {
      aA[i] -= (size_t)KB * 512;
      aB[i] += (size_t)(NT - 1) * KB * 512;
    }
  }

  // Coalesced epilogue via per-wave private LDS transpose (no barrier needed).
  // C/D layout: col = lane&15, row = quad*4 + reg (m89/m91 verified).
  u16* Ps = P + (size_t)blockIdx.z * ((size_t)BATCH * N);
  u16* lw = &ls[w * 2048];   // 32 rows x 64 cols u16, per wave
  #pragma unroll
  for (int half = 0; half < 2; ++half) {
    #pragma unroll
    for (int mh = 0; mh < 2; ++mh) {
      int mt = half * 2 + mh;
      #pragma unroll
      for (int r = 0; r < 4; ++r) {
        int rloc = mh * 16 + quad * 4 + r;          // 0..31
        #pragma unroll
        for (int nt = 0; nt < 4; ++nt) {
          int col = nt * 16 + lrow;                 // 0..63
          int c8 = (col >> 3) ^ (rloc & 7);         // XOR-8 chunk swizzle
          lw[rloc * 64 + (c8 << 3) + (col & 7)] = f2bf(acc[mt][nt][r]);
        }
      }
    }
    #pragma unroll
    for (int p = 0; p < 4; ++p) {
      int rloc = p * 8 + (lane >> 3);               // 0..31
      int c8 = (lane & 7) ^ (rloc & 7);
      u16x8 vv = *(const u16x8*)&lw[rloc * 64 + (c8 << 3)];
      int row = row0 + wm * 64 + half * 32 + rloc;
      int colg = col0 + wn * 64 + ((lane & 7) << 3);
      *(u16x8*)&Ps[(size_t)row * N + colg] = vv;
    }
  }
}

extern "C" void kernel_launch(void* const* d_in, const int* in_sizes, int n_in,
                              void* d_out, int out_size, void* d_ws, size_t ws_size,
                              hipStream_t stream) {
  const float* blend = (const float*)d_in[0];
  const float* x  = (const float*)d_in[1];
  const float* W0 = (const float*)d_in[2];
  const float* B0 = (const float*)d_in[3];
  const float* W1 = (const float*)d_in[4];
  const float* B1 = (const float*)d_in[5];
  const float* W2 = (const float*)d_in[6];
  const float* B2 = (const float*)d_in[7];
  float* out = (float*)d_out;

  char* ws = (char*)d_ws;
  u16* hA  = (u16*)ws;                           // frag-major h0 (4 MB) then h2 (8.4 MB)
  u16* h1  = (u16*)(ws + 8388608);               // frag-major h1, 8.4 MB
  u16* Bt0 = (u16*)(ws + 16777216);              // frag-major, 8.4 MB
  u16* Bt1 = (u16*)(ws + 25165824);              // frag-major, 16.8 MB
  u16* Bt2 = (u16*)(ws + 41943040);              // frag-major, 8.4 MB
  u16* P   = (u16*)(ws + 50331648);              // bf16 partial slices, row-major

  // prep: x -> h0 frag-major; W0/W1/W2 -> frag-major bf16 (one dispatch)
  prep_kernel<<<9216, 256, 0, stream>>>(x, W0, W1, W2, hA, Bt0, Bt1, Bt2);

  // Layer 0: K0=512, N=1024; 2 slices x 4 experts; bias+ELU in combine
  gemm_ff_kernel<512, 4><<<dim3(32, 8, 2), 256, 0, stream>>>(hA, Bt0, blend, P, 1024);
  combineS_kernel<2, true, 1024><<<2048, 256, 0, stream>>>(P, blend, B0, h1, 1024);

  // Layer 1: K0=1024, N=1024; 2 slices x 4 experts
  gemm_ff_kernel<1024, 4><<<dim3(32, 8, 2), 256, 0, stream>>>(h1, Bt1, blend, P, 1024);
  combineS_kernel<2, true, 1024><<<2048, 256, 0, stream>>>(P, blend, B1, hA, 1024);

  // Layer 2: K0=1024, N=512; 4 slices x 2 experts; linear, fp32 out
  gemm_ff_kernel<1024, 2><<<dim3(32, 4, 4), 256, 0, stream>>>(hA, Bt2, blend, P, 512);
  combineS_kernel<4, false, 0><<<1024, 256, 0, stream>>>(P, blend, B2, out, 512);
}